// Round 4
// baseline (730.306 us; speedup 1.0000x reference)
//
#include <hip/hip_runtime.h>
#include <hip/hip_cooperative_groups.h>

namespace cg = cooperative_groups;

#define N_NEUR 256
#define N_EDGE 1024
#define BATCH  128
#define HWDIM  28
#define IMG    784
#define FCH    200
#define NCLS   10
#define INF_W  0x3fffffff

#define MAX_NB 1024
#define NT 256
#define NUM_CU 256       // MI355X
#define SLOTS 257        // 256 neurons + 1 slot for staged x
#define XSLOT 256
#define TSZ   1024       // padded 32x32 tile, elems
#define CELLS 98         // 7 x-chunks * 14 y-chunks (4x2 px per thread)
#define UNITS_PER_NODE (BATCH * CELLS)   // 12544

__device__ __forceinline__ unsigned short f2bf(float v) {
    unsigned u = __float_as_uint(v);
    return (unsigned short)((u + 0x7FFFu + ((u >> 16) & 1u)) >> 16);
}

template<bool F32>
__device__ __forceinline__ void loadRow8(const void* p, float f[8]) {
    if constexpr (F32) {
        const float4* q = (const float4*)p;
        float4 a = q[0], b = q[1];
        f[0]=a.x; f[1]=a.y; f[2]=a.z; f[3]=a.w;
        f[4]=b.x; f[5]=b.y; f[6]=b.z; f[7]=b.w;
    } else {
        const uint2* q = (const uint2*)p;
        uint2 a = q[0], b = q[1];
        f[0]=__uint_as_float(a.x << 16); f[1]=__uint_as_float(a.x & 0xFFFF0000u);
        f[2]=__uint_as_float(a.y << 16); f[3]=__uint_as_float(a.y & 0xFFFF0000u);
        f[4]=__uint_as_float(b.x << 16); f[5]=__uint_as_float(b.x & 0xFFFF0000u);
        f[6]=__uint_as_float(b.y << 16); f[7]=__uint_as_float(b.y & 0xFFFF0000u);
    }
}

template<bool F32>
__device__ __forceinline__ void load4(const void* p, float f[4]) {
    if constexpr (F32) {
        const float2* q = (const float2*)p;
        float2 a = q[0], b = q[1];
        f[0]=a.x; f[1]=a.y; f[2]=b.x; f[3]=b.y;
    } else {
        const unsigned* q = (const unsigned*)p;
        unsigned a = q[0], b = q[1];
        f[0]=__uint_as_float(a << 16); f[1]=__uint_as_float(a & 0xFFFF0000u);
        f[2]=__uint_as_float(b << 16); f[3]=__uint_as_float(b & 0xFFFF0000u);
    }
}

template<bool F32>
__device__ __forceinline__ void store4(void* p, float a0, float a1, float a2, float a3) {
    if constexpr (F32) {
        float2* q = (float2*)p;
        q[0] = make_float2(a0, a1);
        q[1] = make_float2(a2, a3);
    } else {
        unsigned* q = (unsigned*)p;
        q[0] = (unsigned)f2bf(a0) | ((unsigned)f2bf(a1) << 16);
        q[1] = (unsigned)f2bf(a2) | ((unsigned)f2bf(a3) << 16);
    }
}

template<bool F32>
__global__ __launch_bounds__(NT, 4)
void net_kernel(const float* __restrict__ x, const int* __restrict__ src,
                const int* __restrict__ tgt,
                const float* __restrict__ conv_w, const float* __restrict__ conv_b,
                const float* __restrict__ fc1_w, const float* __restrict__ fc1_b,
                const float* __restrict__ fc2_w, const float* __restrict__ fc2_b,
                float* __restrict__ dout, char* __restrict__ wsc,
                int cmax, int dlast)
{
    using ST = typename std::conditional<F32, float, unsigned short>::type;
    cg::grid_group grid = cg::this_grid();
    const int tid   = threadIdx.x;
    const int gt    = blockIdx.x * NT + tid;
    const int gsize = gridDim.x * NT;

    ST* act = (ST*)wsc;
    const size_t actElems = (size_t)SLOTS * BATCH * TSZ;
    float* hidden = (float*)(wsc + actElems * sizeof(ST));
    int* ib        = (int*)(hidden + BATCH * FCH);
    int* inact     = ib;            // [256]
    int* waveOff   = ib + 256;      // [320]
    int* waveNodes = ib + 576;      // [256]
    int* iwaveG    = ib + 832;      // [256]
    int* iidx      = ib + 1088;             // [256*cmax]
    int* iact      = iidx + N_NEUR * cmax;  // [256*cmax] packed u | (c<<9)

    __shared__ int s_src[N_EDGE];
    __shared__ int s_tgt[N_EDGE];
    __shared__ int s_wave[N_NEUR];
    __shared__ int s_done;

    // ================= phase 0: schedule (block 0) | halo-zero + x-stage (others) ===========
    if (blockIdx.x == 0) {
        for (int e = tid; e < N_EDGE; e += NT) { s_src[e] = src[e]; s_tgt[e] = tgt[e]; }
        s_wave[tid] = (tid == 0) ? 0 : INF_W;
        __syncthreads();
        // ordered in-list for neuron tid
        int d = 0;
        for (int e = 0; e < N_EDGE; ++e)
            if (s_tgt[e] == tid) { iidx[tid * cmax + d] = s_src[e]; ++d; }
        __syncthreads();
        // BFS waves from neuron 0, stop when 255 assigned
        for (int w = 0; w < 256; ++w) {
            if (tid == 0) s_done = (s_wave[N_NEUR - 1] != INF_W);
            __syncthreads();
            if (s_done) break;
            for (int e = tid; e < N_EDGE; e += NT) {
                int s = s_src[e], t = s_tgt[e];
                if (s_wave[s] == w && s_wave[t] == INF_W) s_wave[t] = w + 1;
            }
            __syncthreads();
        }
        // compact active channels (wave[u] < wave[v]); others contribute exact zeros
        {
            const int wv = s_wave[tid];
            int na = 0;
            for (int c = 0; c < d; ++c) {
                int u = iidx[tid * cmax + c];
                if (s_wave[u] < wv) iact[tid * cmax + na++] = u | (c << 9);
            }
            inact[tid] = na;
            if (tid == 0) { iact[0] = XSLOT; inact[0] = 1; }  // neuron 0 reads staged x
        }
        __syncthreads();
        {
            const int Wl = s_wave[N_NEUR - 1];
            for (int t2 = tid; t2 <= Wl + 1; t2 += NT) {
                int cn = 0;
                for (int v = 0; v < N_NEUR - 1; ++v) if (s_wave[v] < t2) ++cn;
                waveOff[t2] = cn;
            }
            const int v = tid;
            if (v < N_NEUR - 1 && s_wave[v] != INF_W) {
                const int wv = s_wave[v];
                int pos = 0;
                for (int v2 = 0; v2 < N_NEUR - 1; ++v2) {
                    int w2 = s_wave[v2];
                    if (w2 < wv || (w2 == wv && v2 < v)) ++pos;
                }
                waveNodes[pos] = v;
            }
            iwaveG[tid] = s_wave[tid];
        }
    } else {
        const int base   = (blockIdx.x - 1) * NT + tid;
        const int stride = (gridDim.x - 1) * NT;
        // zero halos of all tiles (interior is always written before read)
        const int NTILE = SLOTS * BATCH;           // 32896
        for (int u = base; u < NTILE * 72; u += stride) {
            int t = u % 72;
            ST* tp = act + ((size_t)(u / 72) << 10);
            if (t < 16) {   // rows 0,1 and 30,31 : 8-elem chunks
                int eb = (t < 8) ? t * 8 : 960 + (t - 8) * 8;
                if constexpr (F32) {
                    float4 z = make_float4(0.f, 0.f, 0.f, 0.f);
                    ((float4*)(tp + eb))[0] = z; ((float4*)(tp + eb))[1] = z;
                } else {
                    uint4 z = {0u, 0u, 0u, 0u};
                    *((uint4*)(tp + eb)) = z;
                }
            } else {        // side cols {0,1} and {30,31} of rows 2..29
                int s = t - 16;
                int eb = (2 + (s >> 1)) * 32 + ((s & 1) ? 30 : 0);
                if constexpr (F32) { *((float2*)(tp + eb)) = make_float2(0.f, 0.f); }
                else               { *((unsigned*)(tp + eb)) = 0u; }
            }
        }
        // stage x into padded tiles at slot XSLOT
        for (int u = base; u < BATCH * 196; u += stride) {
            int b = u / 196, ch = u - b * 196;
            int row = ch / 7, col = (ch - row * 7) * 4;
            float4 v4 = *(const float4*)(x + b * IMG + row * HWDIM + col);
            ST* tp = act + (((size_t)(XSLOT * BATCH + b)) << 10) + (row + 2) * 32 + col + 2;
            store4<F32>(tp, v4.x, v4.y, v4.z, v4.w);
        }
    }
    grid.sync();

    const int W = iwaveG[N_NEUR - 1];

    // ================= conv waves: thread = (node, batch, 4x2-pixel cell) =================
    for (int w = 0; w <= W; ++w) {
        const int off   = waveOff[w];
        const int cnt   = waveOff[w + 1] - off;
        const int total = cnt * UNITS_PER_NODE;
        for (int i = gt; i < total; i += gsize) {
            const int ni   = i / UNITS_PER_NODE;
            const int rem  = i - ni * UNITS_PER_NODE;
            const int b    = rem / CELLS;
            const int cell = rem - b * CELLS;
            const int v    = waveNodes[off + ni];
            const int y0   = (cell / 7) * 2;
            const int xs   = (cell - (cell / 7) * 7) * 4;

            const float bias = conv_b[v];
            float acc[8];
            #pragma unroll
            for (int k = 0; k < 8; ++k) acc[k] = bias;

            const int  na = inact[v];
            const int* av = iact + v * cmax;
            for (int a = 0; a < na; ++a) {
                const int pk = av[a];
                const int u  = pk & 511;
                const int c  = pk >> 9;
                const ST* tp = act + ((size_t)(u * BATCH + b) << 10);
                const float* wp = conv_w + ((size_t)v * cmax + c) * 25;
                float wgt[25];
                #pragma unroll
                for (int k = 0; k < 25; ++k) wgt[k] = wp[k];
                #pragma unroll
                for (int r = 0; r < 6; ++r) {
                    float f[8];
                    loadRow8<F32>(tp + (y0 + r) * 32 + xs, f);
                    if (r < 5) {
                        #pragma unroll
                        for (int dx = 0; dx < 5; ++dx)
                            #pragma unroll
                            for (int j = 0; j < 4; ++j)
                                acc[j] = fmaf(f[j + dx], wgt[r * 5 + dx], acc[j]);
                    }
                    if (r > 0) {
                        #pragma unroll
                        for (int dx = 0; dx < 5; ++dx)
                            #pragma unroll
                            for (int j = 0; j < 4; ++j)
                                acc[4 + j] = fmaf(f[j + dx], wgt[(r - 1) * 5 + dx], acc[4 + j]);
                    }
                }
            }
            ST* op = act + ((size_t)(v * BATCH + b) << 10) + (y0 + 2) * 32 + xs + 2;
            store4<F32>(op, fmaxf(acc[0], 0.f), fmaxf(acc[1], 0.f),
                            fmaxf(acc[2], 0.f), fmaxf(acc[3], 0.f));
            store4<F32>(op + 32, fmaxf(acc[4], 0.f), fmaxf(acc[5], 0.f),
                                 fmaxf(acc[6], 0.f), fmaxf(acc[7], 0.f));
        }
        grid.sync();
    }

    // ================= FC1: 8 lanes per (b,h), float4 weights, shuffle reduce (grid-stride) ==
    {
        const int  naL = inact[N_NEUR - 1];
        const int* av  = iact + (N_NEUR - 1) * cmax;
        const int sub  = gt & 7;
        for (int pair = gt >> 3; pair < BATCH * FCH; pair += (gsize >> 3)) {
            const int b = pair & (BATCH - 1);
            const int h = pair >> 7;
            float s = 0.0f;
            for (int a = 0; a < naL; ++a) {
                const int pk = av[a];
                const int u  = pk & 511;
                const int k  = pk >> 9;
                const ST* tp = act + ((size_t)(u * BATCH + b) << 10);
                const float* wr = fc1_w + (size_t)h * ((size_t)dlast * IMG) + (size_t)k * IMG;
                for (int q = sub; q < 196; q += 8) {
                    const int j = q * 4;
                    const int r = j / HWDIM;
                    const int c = j - r * HWDIM;
                    float4 wv = *(const float4*)(wr + j);
                    float f[4];
                    load4<F32>(tp + (r + 2) * 32 + c + 2, f);
                    s = fmaf(f[0], wv.x, s); s = fmaf(f[1], wv.y, s);
                    s = fmaf(f[2], wv.z, s); s = fmaf(f[3], wv.w, s);
                }
            }
            s += __shfl_xor(s, 1, 8);
            s += __shfl_xor(s, 2, 8);
            s += __shfl_xor(s, 4, 8);
            if (sub == 0) hidden[b * FCH + h] = fmaxf(s + fc1_b[h], 0.0f);
        }
    }
    grid.sync();

    // ================= FC2 + log_softmax =================
    if (gt < BATCH) {
        const int bb = gt;
        float lg[NCLS];
        float m = -1e30f;
        const float* hr = hidden + bb * FCH;
        #pragma unroll
        for (int c = 0; c < NCLS; ++c) {
            float a2 = fc2_b[c];
            const float* wr = fc2_w + c * FCH;
            for (int h = 0; h < FCH; ++h) a2 = fmaf(hr[h], wr[h], a2);
            lg[c] = a2;
            m = fmaxf(m, a2);
        }
        float s = 0.0f;
        #pragma unroll
        for (int c = 0; c < NCLS; ++c) s += expf(lg[c] - m);
        const float ls = m + logf(s);
        #pragma unroll
        for (int c = 0; c < NCLS; ++c) dout[bb * NCLS + c] = lg[c] - ls;
    }
}

extern "C" void kernel_launch(void* const* d_in, const int* in_sizes, int n_in,
                              void* d_out, int out_size, void* d_ws, size_t ws_size,
                              hipStream_t stream) {
    const float* x      = (const float*)d_in[0];
    const int*   src    = (const int*)d_in[1];
    const int*   tgt    = (const int*)d_in[2];
    const float* conv_w = (const float*)d_in[3];
    const float* conv_b = (const float*)d_in[4];
    const float* fc1_w  = (const float*)d_in[5];
    const float* fc1_b  = (const float*)d_in[6];
    const float* fc2_w  = (const float*)d_in[7];
    const float* fc2_b  = (const float*)d_in[8];
    float* out = (float*)d_out;
    char*  wsc = (char*)d_ws;

    int cmax  = in_sizes[3] / (N_NEUR * 25);
    int dlast = in_sizes[5] / (FCH * IMG);

    // choose fp32 tiles if workspace allows, else bf16
    size_t intBytes = ((size_t)1088 + 2 * (size_t)N_NEUR * cmax) * 4;
    size_t need32 = (size_t)SLOTS * BATCH * TSZ * 4 + (size_t)BATCH * FCH * 4 + intBytes;
    const bool useF32 = (ws_size >= need32);

    void* kargs[] = { (void*)&x, (void*)&src, (void*)&tgt, (void*)&conv_w, (void*)&conv_b,
                      (void*)&fc1_w, (void*)&fc1_b, (void*)&fc2_w, (void*)&fc2_b,
                      (void*)&out, (void*)&wsc, (void*)&cmax, (void*)&dlast };

    void* kfn = useF32 ? (void*)net_kernel<true> : (void*)net_kernel<false>;

    // Clamp grid to the runtime's cooperative co-residency limit (R2 lesson:
    // a too-large cooperative launch fails SILENTLY if the error is ignored).
    int occ = 0;
    hipError_t qerr = hipOccupancyMaxActiveBlocksPerMultiprocessor(&occ, kfn, NT, 0);
    if (qerr != hipSuccess || occ < 1) occ = 1;
    int nb = occ * NUM_CU;
    if (nb > MAX_NB) nb = MAX_NB;

    // Deterministic fallback: halve until the launch is accepted.
    for (int attempt = 0; attempt < 6; ++attempt) {
        hipError_t lerr = hipLaunchCooperativeKernel(kfn, dim3(nb), dim3(NT), kargs, 0, stream);
        if (lerr == hipSuccess) break;
        nb = (nb > 64) ? nb / 2 : 64;
    }
}

// Round 5
// 498.694 us; speedup vs baseline: 1.4644x; 1.4644x over previous
//
#include <hip/hip_runtime.h>
#include <hip/hip_cooperative_groups.h>

namespace cg = cooperative_groups;

#define N_NEUR 256
#define N_EDGE 1024
#define BATCH  128
#define HWDIM  28
#define IMG    784
#define FCH    200
#define NCLS   10
#define INF_W  0x3fffffff

#define MAX_NB 768
#define NT 256
#define NUM_CU 256
#define SLOTS 257        // 256 neurons + 1 slot for staged x
#define XSLOT 256
#define TSZ   1024       // padded 32x32 tile, elems
#define CHUNK 8          // channels staged in LDS at once (8 x 4KB = 32KB)

// swizzled LDS float-index for (row, col) in a 32x32 tile: XOR col bits>=2
// with row&7 -> spreads same-col accesses across banks, keeps 8B/16B alignment
__device__ __forceinline__ int lcol(int row, int col) {
    return (row << 5) + (col ^ ((row & 7) << 2));
}

__global__ __launch_bounds__(NT, 4)
void net_kernel(const float* __restrict__ x, const int* __restrict__ src,
                const int* __restrict__ tgt,
                const float* __restrict__ conv_w, const float* __restrict__ conv_b,
                const float* __restrict__ fc1_w, const float* __restrict__ fc1_b,
                const float* __restrict__ fc2_w, const float* __restrict__ fc2_b,
                float* __restrict__ dout, char* __restrict__ wsc,
                int cmax, int dlast)
{
    cg::grid_group grid = cg::this_grid();
    const int tid   = threadIdx.x;
    const int gt    = blockIdx.x * NT + tid;
    const int gsize = gridDim.x * NT;
    const int nb    = gridDim.x;

    float* act = (float*)wsc;                                  // [SLOTS*BATCH][1024]
    float* hidden = act + (size_t)SLOTS * BATCH * TSZ;         // [128][200]
    int* ib        = (int*)(hidden + BATCH * FCH);
    int* inact     = ib;            // [256]
    int* waveOff   = ib + 256;      // [320]
    int* waveNodes = ib + 576;      // [256]
    int* iwaveG    = ib + 832;      // [256]
    int* gbarctr   = ib + 1088;     // [1] custom grid-barrier counter
    int* iidx      = ib + 1152;             // [256*cmax]
    int* iact      = iidx + N_NEUR * cmax;  // [256*cmax] packed u | (c<<9)

    __shared__ float s_tiles[CHUNK][TSZ];   // 32KB, aliased by schedule arrays in phase 0
    __shared__ float s_wgt[CHUNK * 26];
    __shared__ int   s_done;

    // ================= phase 0: schedule (block 0) | halo-zero + x-stage (others) ==========
    if (blockIdx.x == 0) {
        int* s_src  = (int*)&s_tiles[0][0];
        int* s_tgt  = s_src + N_EDGE;
        int* s_wave = s_tgt + N_EDGE;
        for (int e = tid; e < N_EDGE; e += NT) { s_src[e] = src[e]; s_tgt[e] = tgt[e]; }
        s_wave[tid] = (tid == 0) ? 0 : INF_W;
        if (tid == 0) *gbarctr = 0;
        __syncthreads();
        int d = 0;
        for (int e = 0; e < N_EDGE; ++e)
            if (s_tgt[e] == tid) { iidx[tid * cmax + d] = s_src[e]; ++d; }
        __syncthreads();
        for (int w = 0; w < 256; ++w) {
            if (tid == 0) s_done = (s_wave[N_NEUR - 1] != INF_W);
            __syncthreads();
            if (s_done) break;
            for (int e = tid; e < N_EDGE; e += NT) {
                int s = s_src[e], t = s_tgt[e];
                if (s_wave[s] == w && s_wave[t] == INF_W) s_wave[t] = w + 1;
            }
            __syncthreads();
        }
        {   // compact active channels (wave[u] < wave[v]); inactive contribute exact zeros
            const int wv = s_wave[tid];
            int na = 0;
            for (int c = 0; c < d; ++c) {
                int u = iidx[tid * cmax + c];
                if (s_wave[u] < wv) iact[tid * cmax + na++] = u | (c << 9);
            }
            inact[tid] = na;
            if (tid == 0) { iact[0] = XSLOT; inact[0] = 1; }
        }
        __syncthreads();
        {
            const int Wl = s_wave[N_NEUR - 1];
            for (int t2 = tid; t2 <= Wl + 1; t2 += NT) {
                int cn = 0;
                for (int v = 0; v < N_NEUR - 1; ++v) if (s_wave[v] < t2) ++cn;
                waveOff[t2] = cn;
            }
            const int v = tid;
            if (v < N_NEUR - 1 && s_wave[v] != INF_W) {
                const int wv = s_wave[v];
                int pos = 0;
                for (int v2 = 0; v2 < N_NEUR - 1; ++v2) {
                    int w2 = s_wave[v2];
                    if (w2 < wv || (w2 == wv && v2 < v)) ++pos;
                }
                waveNodes[pos] = v;
            }
            iwaveG[tid] = s_wave[tid];
        }
    } else {
        const int base   = (blockIdx.x - 1) * NT + tid;
        const int stride = (nb - 1) * NT;
        const int NTILE  = SLOTS * BATCH;
        // zero halos (interior always written before read)
        for (int u = base; u < NTILE * 72; u += stride) {
            int t = u % 72;
            float* tp = act + ((size_t)(u / 72) << 10);
            if (t < 16) {
                int eb = (t < 8) ? t * 8 : 960 + (t - 8) * 8;
                float4 z = make_float4(0.f, 0.f, 0.f, 0.f);
                ((float4*)(tp + eb))[0] = z; ((float4*)(tp + eb))[1] = z;
            } else {
                int s = t - 16;
                int eb = (2 + (s >> 1)) * 32 + ((s & 1) ? 30 : 0);
                *((float2*)(tp + eb)) = make_float2(0.f, 0.f);
            }
        }
        // stage x into padded tiles at slot XSLOT
        for (int u = base; u < BATCH * 196; u += stride) {
            int b = u / 196, ch = u - b * 196;
            int row = ch / 7, col = (ch - row * 7) * 4;
            float4 v4 = *(const float4*)(x + b * IMG + row * HWDIM + col);
            float* tp = act + (((size_t)(XSLOT * BATCH + b)) << 10) + (row + 2) * 32 + col + 2;
            tp[0] = v4.x; tp[1] = v4.y; tp[2] = v4.z; tp[3] = v4.w;
        }
    }
    grid.sync();   // also publishes gbarctr=0 for the custom barrier

    const int W = iwaveG[N_NEUR - 1];
    int gen = 0;   // custom-barrier generation (thread 0 of each block)

    // cell: 2x2 output pixels; 196 cells cover 28x28
    const int cy = tid / 14, cx = tid - (tid / 14) * 14;
    const int y0 = cy * 2, x0 = cx * 2;
    const bool cellAct = (tid < 196);

    // ================= conv waves (LDS-staged) + FC1 merged into wave W ====================
    for (int w = 0; w <= W; ++w) {
        const int off   = waveOff[w];
        const int cnt   = waveOff[w + 1] - off;
        const int total = cnt << 7;                    // units = (node, b)
        for (int unit = blockIdx.x; unit < total; unit += nb) {
            const int ni = unit >> 7;
            const int b  = unit & (BATCH - 1);
            const int v  = waveNodes[off + ni];
            const int na = inact[v];
            const int* av = iact + v * cmax;
            const float bias = conv_b[v];
            float acc[4] = {bias, bias, bias, bias};

            for (int cb = 0; cb < na; cb += CHUNK) {
                const int nc = (na - cb < CHUNK) ? (na - cb) : CHUNK;
                __syncthreads();   // protect LDS from previous chunk's readers
                // ---- stage nc tiles + weights (parallel loads, one latency wait) ----
                float4 stg[CHUNK];
                #pragma unroll
                for (int c2 = 0; c2 < CHUNK; ++c2) {
                    if (c2 < nc) {
                        const int u = av[cb + c2] & 511;
                        stg[c2] = *(const float4*)(act + (((size_t)(u * BATCH + b)) << 10) + (tid << 2));
                    }
                }
                if (tid < nc * 25) {
                    const int c2 = tid / 25, k = tid - c2 * 25;
                    const int cc = av[cb + c2] >> 9;
                    s_wgt[c2 * 26 + k] = conv_w[((size_t)v * cmax + cc) * 25 + k];
                }
                {
                    const int g = tid >> 3, cg4 = (tid & 7) << 2;
                    const int di = (g << 5) + (cg4 ^ ((g & 7) << 2));
                    #pragma unroll
                    for (int c2 = 0; c2 < CHUNK; ++c2)
                        if (c2 < nc) *(float4*)&s_tiles[c2][di] = stg[c2];
                }
                __syncthreads();
                // ---- compute from LDS ----
                if (cellAct) {
                    for (int c2 = 0; c2 < nc; ++c2) {
                        float wg[25];
                        #pragma unroll
                        for (int k = 0; k < 25; ++k) wg[k] = s_wgt[c2 * 26 + k];
                        const float* T = &s_tiles[c2][0];
                        #pragma unroll
                        for (int r = 0; r < 6; ++r) {
                            const int row = y0 + r;
                            float2 p0 = *(const float2*)&T[lcol(row, x0)];
                            float2 p1 = *(const float2*)&T[lcol(row, x0 + 2)];
                            float2 p2 = *(const float2*)&T[lcol(row, x0 + 4)];
                            float f[6] = {p0.x, p0.y, p1.x, p1.y, p2.x, p2.y};
                            #pragma unroll
                            for (int i = 0; i < 2; ++i) {
                                const int wr = r - i;
                                if (wr < 0 || wr > 4) continue;
                                #pragma unroll
                                for (int j = 0; j < 2; ++j)
                                    #pragma unroll
                                    for (int dx = 0; dx < 5; ++dx)
                                        acc[i * 2 + j] = fmaf(f[j + dx], wg[wr * 5 + dx], acc[i * 2 + j]);
                            }
                        }
                    }
                }
            }
            if (cellAct) {
                float* op = act + (((size_t)(v * BATCH + b)) << 10) + (y0 + 2) * 32 + x0 + 2;
                *(float2*)op        = make_float2(fmaxf(acc[0], 0.f), fmaxf(acc[1], 0.f));
                *(float2*)(op + 32) = make_float2(fmaxf(acc[2], 0.f), fmaxf(acc[3], 0.f));
            }
        }

        // FC1 overlapped with wave W (reads only pre-wave-W activations)
        if (w == W) {
            const int  naL = inact[N_NEUR - 1];
            const int* av  = iact + (N_NEUR - 1) * cmax;
            const int sub  = gt & 7;
            for (int pair = gt >> 3; pair < BATCH * FCH; pair += (gsize >> 3)) {
                const int b = pair & (BATCH - 1);
                const int h = pair >> 7;
                float s = 0.0f;
                for (int a = 0; a < naL; ++a) {
                    const int pk = av[a];
                    const int u  = pk & 511;
                    const int k  = pk >> 9;
                    const float* tp = act + (((size_t)(u * BATCH + b)) << 10);
                    const float* wr = fc1_w + (size_t)h * ((size_t)dlast * IMG) + (size_t)k * IMG;
                    #pragma unroll 2
                    for (int q = sub; q < 196; q += 8) {
                        const int j = q * 4;
                        const int r = j / HWDIM;
                        const int c = j - r * HWDIM;
                        float4 wv = *(const float4*)(wr + j);
                        const float* ap = tp + (r + 2) * 32 + c + 2;
                        float2 a0 = *(const float2*)ap;
                        float2 a1 = *(const float2*)(ap + 2);
                        s = fmaf(a0.x, wv.x, s); s = fmaf(a0.y, wv.y, s);
                        s = fmaf(a1.x, wv.z, s); s = fmaf(a1.y, wv.w, s);
                    }
                }
                s += __shfl_xor(s, 1, 8);
                s += __shfl_xor(s, 2, 8);
                s += __shfl_xor(s, 4, 8);
                if (sub == 0) hidden[b * FCH + h] = fmaxf(s + fc1_b[h], 0.0f);
            }
        }

        // ---- lightweight grid barrier (agent-scope atomic + generation spin) ----
        __syncthreads();
        if (tid == 0) {
            ++gen;
            __hip_atomic_fetch_add(gbarctr, 1, __ATOMIC_ACQ_REL, __HIP_MEMORY_SCOPE_AGENT);
            const int target = gen * nb;
            while (__hip_atomic_load(gbarctr, __ATOMIC_ACQUIRE, __HIP_MEMORY_SCOPE_AGENT) < target)
                __builtin_amdgcn_s_sleep(2);
        }
        __syncthreads();
    }

    // ================= FC2 + log_softmax =================
    if (gt < BATCH) {
        const int bb = gt;
        float lg[NCLS];
        float m = -1e30f;
        const float* hr = hidden + bb * FCH;
        #pragma unroll
        for (int c = 0; c < NCLS; ++c) {
            float a2 = fc2_b[c];
            const float* wr = fc2_w + c * FCH;
            for (int h = 0; h < FCH; ++h) a2 = fmaf(hr[h], wr[h], a2);
            lg[c] = a2;
            m = fmaxf(m, a2);
        }
        float s = 0.0f;
        #pragma unroll
        for (int c = 0; c < NCLS; ++c) s += expf(lg[c] - m);
        const float ls = m + logf(s);
        #pragma unroll
        for (int c = 0; c < NCLS; ++c) dout[bb * NCLS + c] = lg[c] - ls;
    }
}

extern "C" void kernel_launch(void* const* d_in, const int* in_sizes, int n_in,
                              void* d_out, int out_size, void* d_ws, size_t ws_size,
                              hipStream_t stream) {
    const float* x      = (const float*)d_in[0];
    const int*   src    = (const int*)d_in[1];
    const int*   tgt    = (const int*)d_in[2];
    const float* conv_w = (const float*)d_in[3];
    const float* conv_b = (const float*)d_in[4];
    const float* fc1_w  = (const float*)d_in[5];
    const float* fc1_b  = (const float*)d_in[6];
    const float* fc2_w  = (const float*)d_in[7];
    const float* fc2_b  = (const float*)d_in[8];
    float* out = (float*)d_out;
    char*  wsc = (char*)d_ws;

    int cmax  = in_sizes[3] / (N_NEUR * 25);
    int dlast = in_sizes[5] / (FCH * IMG);

    void* kargs[] = { (void*)&x, (void*)&src, (void*)&tgt, (void*)&conv_w, (void*)&conv_b,
                      (void*)&fc1_w, (void*)&fc1_b, (void*)&fc2_w, (void*)&fc2_b,
                      (void*)&out, (void*)&wsc, (void*)&cmax, (void*)&dlast };
    void* kfn = (void*)net_kernel;

    int occ = 0;
    hipError_t qerr = hipOccupancyMaxActiveBlocksPerMultiprocessor(&occ, kfn, NT, 0);
    if (qerr != hipSuccess || occ < 1) occ = 1;
    int nbl = occ * NUM_CU;
    if (nbl > MAX_NB) nbl = MAX_NB;

    for (int attempt = 0; attempt < 6; ++attempt) {
        hipError_t lerr = hipLaunchCooperativeKernel(kfn, dim3(nbl), dim3(NT), kargs, 0, stream);
        if (lerr == hipSuccess) break;
        nbl = (nbl > 64) ? nbl / 2 : 64;
    }
}

// Round 7
// 391.264 us; speedup vs baseline: 1.8665x; 1.2746x over previous
//
#include <hip/hip_runtime.h>
#include <hip/hip_cooperative_groups.h>

namespace cg = cooperative_groups;

#define N_NEUR 256
#define N_EDGE 1024
#define BATCH  128
#define HWDIM  28
#define IMG    784
#define FCH    200
#define NCLS   10
#define INF_W  0x3fffffff

#define MAX_NB 768
#define NT 256
#define NUM_CU 256
#define SLOTS 257        // 256 neurons + 1 slot for staged x
#define XSLOT 256
#define TSZ   1024       // padded 32x32 tile, floats
#define CHUNK 4          // conv channels per LDS round (x BPER batches)
#define FCHUNK 8         // fc1 channels per LDS round
#define BPER  2
#define CONV_TARGET (BATCH / BPER)   // 64 units produce one node

// ---- agent-scope (device-coherent) accesses for the act buffer ----
__device__ __forceinline__ float2 ldg2(const float* p) {
    unsigned long long u = __hip_atomic_load((const unsigned long long*)p,
        __ATOMIC_RELAXED, __HIP_MEMORY_SCOPE_AGENT);
    float2 r; r.x = __uint_as_float((unsigned)u);
    r.y = __uint_as_float((unsigned)(u >> 32));
    return r;
}
__device__ __forceinline__ void stg2(float* p, float a, float b) {
    unsigned long long u = (unsigned long long)__float_as_uint(a)
                         | ((unsigned long long)__float_as_uint(b) << 32);
    __hip_atomic_store((unsigned long long*)p, u, __ATOMIC_RELAXED,
                       __HIP_MEMORY_SCOPE_AGENT);
}
__device__ __forceinline__ void stg1(float* p, float a) {
    __hip_atomic_store((unsigned*)p, __float_as_uint(a), __ATOMIC_RELAXED,
                       __HIP_MEMORY_SCOPE_AGENT);
}

__device__ __forceinline__ void wait_count(int* f, int target) {
    int spins = 0;
    while (__hip_atomic_load(f, __ATOMIC_RELAXED, __HIP_MEMORY_SCOPE_AGENT) < target) {
        if (spins < 16) __builtin_amdgcn_s_sleep(2);
        else            __builtin_amdgcn_s_sleep(16);
        ++spins;
    }
}

// swizzled LDS float-index for (row,col) of a 32x32 tile (bank-spread, 8B-safe)
__device__ __forceinline__ int lcol(int row, int col) {
    return (row << 5) + (col ^ ((row & 7) << 2));
}

__global__ __launch_bounds__(NT, 4)
void net_kernel(const float* __restrict__ x, const int* __restrict__ src,
                const int* __restrict__ tgt,
                const float* __restrict__ conv_w, const float* __restrict__ conv_b,
                const float* __restrict__ fc1_w, const float* __restrict__ fc1_b,
                const float* __restrict__ fc2_w, const float* __restrict__ fc2_b,
                float* __restrict__ dout, char* __restrict__ wsc,
                int cmax, int dlast)
{
    cg::grid_group grid = cg::this_grid();
    const int tid = threadIdx.x;
    const int nb  = gridDim.x;

    float* act    = (float*)wsc;                            // [SLOTS*BATCH][1024]
    float* hidden = act + (size_t)SLOTS * BATCH * TSZ;      // [128][200]
    int* ib        = (int*)(hidden + BATCH * FCH);
    int* inact     = ib;            // [256]
    int* waveOff   = ib + 256;      // [320]
    int* waveNodes = ib + 576;      // [256]
    int* iwaveG    = ib + 832;      // [256]
    int* nodeDone  = ib + 1088;     // [257] per-node completed-unit count
    int* fcDone    = ib + 1348;     // [1]
    int* iidx      = ib + 1352;             // [256*cmax]
    int* iact      = iidx + N_NEUR * cmax;  // [256*cmax] packed u | (c<<9)

    __shared__ float s_tiles[BPER][CHUNK][TSZ];   // 32KB (aliased in phase 0 / FC1)
    __shared__ float s_wgt[CHUNK * 26];
    __shared__ int   s_done;
    float* s_flat = &s_tiles[0][0][0];

    // ================= phase 0: schedule + flag init (block 0) | halo-zero + x (others) ====
    if (blockIdx.x == 0) {
        int* s_src  = (int*)s_flat;
        int* s_tgt  = s_src + N_EDGE;
        int* s_wave = s_tgt + N_EDGE;
        for (int e = tid; e < N_EDGE; e += NT) { s_src[e] = src[e]; s_tgt[e] = tgt[e]; }
        s_wave[tid] = (tid == 0) ? 0 : INF_W;
        nodeDone[tid] = 0;
        if (tid == 0) { nodeDone[XSLOT] = CONV_TARGET; *fcDone = 0; }
        __syncthreads();
        int d = 0;
        for (int e = 0; e < N_EDGE; ++e)
            if (s_tgt[e] == tid) { iidx[tid * cmax + d] = s_src[e]; ++d; }
        __syncthreads();
        for (int w = 0; w < 256; ++w) {
            if (tid == 0) s_done = (s_wave[N_NEUR - 1] != INF_W);
            __syncthreads();
            if (s_done) break;
            for (int e = tid; e < N_EDGE; e += NT) {
                int s = s_src[e], t = s_tgt[e];
                if (s_wave[s] == w && s_wave[t] == INF_W) s_wave[t] = w + 1;
            }
            __syncthreads();
        }
        {   // compact active channels (wave[u] < wave[v]); inactive contribute exact zeros
            const int wv = s_wave[tid];
            int na = 0;
            for (int c = 0; c < d; ++c) {
                int u = iidx[tid * cmax + c];
                if (s_wave[u] < wv) iact[tid * cmax + na++] = u | (c << 9);
            }
            inact[tid] = na;
            if (tid == 0) { iact[0] = XSLOT; inact[0] = 1; }
        }
        __syncthreads();
        {
            const int Wl = s_wave[N_NEUR - 1];
            for (int t2 = tid; t2 <= Wl + 1; t2 += NT) {
                int cn = 0;
                for (int v = 0; v < N_NEUR - 1; ++v) if (s_wave[v] < t2) ++cn;
                waveOff[t2] = cn;
            }
            const int v = tid;
            if (v < N_NEUR - 1 && s_wave[v] != INF_W) {
                const int wv = s_wave[v];
                int pos = 0;
                for (int v2 = 0; v2 < N_NEUR - 1; ++v2) {
                    int w2 = s_wave[v2];
                    if (w2 < wv || (w2 == wv && v2 < v)) ++pos;
                }
                waveNodes[pos] = v;
            }
            iwaveG[tid] = s_wave[tid];
        }
    } else {
        const int base   = (blockIdx.x - 1) * NT + tid;
        const int stride = (nb - 1) * NT;
        const int NTILE  = SLOTS * BATCH;
        for (int u = base; u < NTILE * 72; u += stride) {   // halos
            int t = u % 72;
            float* tp = act + ((size_t)(u / 72) << 10);
            if (t < 16) {
                int eb = (t < 8) ? t * 8 : 960 + (t - 8) * 8;
                float4 z = make_float4(0.f, 0.f, 0.f, 0.f);
                ((float4*)(tp + eb))[0] = z; ((float4*)(tp + eb))[1] = z;
            } else {
                int s = t - 16;
                int eb = (2 + (s >> 1)) * 32 + ((s & 1) ? 30 : 0);
                *((float2*)(tp + eb)) = make_float2(0.f, 0.f);
            }
        }
        for (int u = base; u < BATCH * 196; u += stride) {  // stage x at XSLOT
            int b = u / 196, ch = u - b * 196;
            int row = ch / 7, col = (ch - row * 7) * 4;
            float4 v4 = *(const float4*)(x + b * IMG + row * HWDIM + col);
            float* tp = act + (((size_t)(XSLOT * BATCH + b)) << 10) + (row + 2) * 32 + col + 2;
            tp[0] = v4.x; tp[1] = v4.y; tp[2] = v4.z; tp[3] = v4.w;
        }
    }
    grid.sync();   // ONLY grid-wide barrier: publishes schedule, halos, x, flags

    const int W         = iwaveG[N_NEUR - 1];
    const int nConv     = waveOff[W + 1];
    const int totalConv = nConv * CONV_TARGET;
    const int totalUnits = totalConv + BATCH + 1;

    const int cy = tid / 14, cx = tid - cy * 14;
    const int y0 = cy * 2, x0 = cx * 2;
    const bool cellAct = (tid < 196);
    const int g = tid >> 3, cg4 = (tid & 7) << 2;
    const int di = (g << 5) + (cg4 ^ ((g & 7) << 2));       // swizzled dest for tid's float4

    // ============== dataflow unit loop (topological static assignment) ==============
    for (int unit = blockIdx.x; unit < totalUnits; unit += nb) {
        if (unit < totalConv) {
            // -------- conv unit: node waveNodes[ni], batches bp, bp+1 --------
            const int ni = unit >> 6;               // CONV_TARGET == 64
            const int bp = (unit & 63) * BPER;
            const int v  = waveNodes[ni];
            const int na = inact[v];
            const int* av = iact + v * cmax;
            if (tid == 0)
                for (int a = 0; a < na; ++a) wait_count(&nodeDone[av[a] & 511], CONV_TARGET);
            __syncthreads();

            const float bias = conv_b[v];
            float acc[BPER][4];
            #pragma unroll
            for (int bb = 0; bb < BPER; ++bb)
                #pragma unroll
                for (int k = 0; k < 4; ++k) acc[bb][k] = bias;

            for (int cb = 0; cb < na; cb += CHUNK) {
                const int nc = (na - cb < CHUNK) ? (na - cb) : CHUNK;
                // issue global loads while previous round's LDS reads drain
                float2 stg[CHUNK][BPER][2];
                #pragma unroll
                for (int c2 = 0; c2 < CHUNK; ++c2) {
                    if (c2 < nc) {
                        const int u2 = av[cb + c2] & 511;
                        #pragma unroll
                        for (int bb = 0; bb < BPER; ++bb) {
                            const float* sp = act + (((size_t)(u2 * BATCH + bp + bb)) << 10) + (tid << 2);
                            stg[c2][bb][0] = ldg2(sp);
                            stg[c2][bb][1] = ldg2(sp + 2);
                        }
                    }
                }
                float wreg = 0.f;
                if (tid < nc * 25) {
                    const int c2 = tid / 25, k = tid - c2 * 25;
                    const int cc = av[cb + c2] >> 9;
                    wreg = conv_w[((size_t)v * cmax + cc) * 25 + k];
                }
                __syncthreads();   // prior LDS readers done
                #pragma unroll
                for (int c2 = 0; c2 < CHUNK; ++c2) {
                    if (c2 < nc) {
                        #pragma unroll
                        for (int bb = 0; bb < BPER; ++bb)
                            *(float4*)&s_tiles[bb][c2][di] =
                                make_float4(stg[c2][bb][0].x, stg[c2][bb][0].y,
                                            stg[c2][bb][1].x, stg[c2][bb][1].y);
                    }
                }
                if (tid < nc * 25) s_wgt[(tid / 25) * 26 + (tid - (tid / 25) * 25)] = wreg;
                __syncthreads();
                if (cellAct) {
                    #pragma unroll
                    for (int bb = 0; bb < BPER; ++bb) {
                        for (int c2 = 0; c2 < nc; ++c2) {
                            float wg[25];
                            #pragma unroll
                            for (int k = 0; k < 25; ++k) wg[k] = s_wgt[c2 * 26 + k];
                            const float* T = &s_tiles[bb][c2][0];
                            #pragma unroll
                            for (int r = 0; r < 6; ++r) {
                                const int row = y0 + r;
                                float2 p0 = *(const float2*)&T[lcol(row, x0)];
                                float2 p1 = *(const float2*)&T[lcol(row, x0 + 2)];
                                float2 p2 = *(const float2*)&T[lcol(row, x0 + 4)];
                                float f[6] = {p0.x, p0.y, p1.x, p1.y, p2.x, p2.y};
                                #pragma unroll
                                for (int i = 0; i < 2; ++i) {
                                    const int wr = r - i;
                                    if (wr < 0 || wr > 4) continue;
                                    #pragma unroll
                                    for (int j = 0; j < 2; ++j)
                                        #pragma unroll
                                        for (int dx = 0; dx < 5; ++dx)
                                            acc[bb][i * 2 + j] =
                                                fmaf(f[j + dx], wg[wr * 5 + dx], acc[bb][i * 2 + j]);
                                }
                            }
                        }
                    }
                }
            }
            if (cellAct) {
                #pragma unroll
                for (int bb = 0; bb < BPER; ++bb) {
                    float* op = act + (((size_t)(v * BATCH + bp + bb)) << 10) + (y0 + 2) * 32 + x0 + 2;
                    stg2(op,      fmaxf(acc[bb][0], 0.f), fmaxf(acc[bb][1], 0.f));
                    stg2(op + 32, fmaxf(acc[bb][2], 0.f), fmaxf(acc[bb][3], 0.f));
                }
            }
            __syncthreads();   // vmcnt(0) drain: all stores globally visible
            if (tid == 0)
                __hip_atomic_fetch_add(&nodeDone[v], 1, __ATOMIC_RELAXED, __HIP_MEMORY_SCOPE_AGENT);

        } else if (unit < totalConv + BATCH) {
            // -------- FC1 unit: one batch b, all 200 hidden --------
            const int b   = unit - totalConv;
            const int naL = inact[N_NEUR - 1];
            const int* av = iact + (N_NEUR - 1) * cmax;
            if (tid == 0)
                for (int a = 0; a < naL; ++a) wait_count(&nodeDone[av[a] & 511], CONV_TARGET);
            __syncthreads();
            float acc = (tid < FCH) ? fc1_b[tid] : 0.f;
            for (int cb = 0; cb < naL; cb += FCHUNK) {
                const int nc = (naL - cb < FCHUNK) ? (naL - cb) : FCHUNK;
                float2 st2[FCHUNK][2];
                #pragma unroll
                for (int c2 = 0; c2 < FCHUNK; ++c2) {
                    if (c2 < nc) {
                        const int u2 = av[cb + c2] & 511;
                        const float* sp = act + (((size_t)(u2 * BATCH + b)) << 10) + (tid << 2);
                        st2[c2][0] = ldg2(sp);
                        st2[c2][1] = ldg2(sp + 2);
                    }
                }
                __syncthreads();
                #pragma unroll
                for (int c2 = 0; c2 < FCHUNK; ++c2)
                    if (c2 < nc)
                        *(float4*)(s_flat + c2 * TSZ + (tid << 2)) =
                            make_float4(st2[c2][0].x, st2[c2][0].y, st2[c2][1].x, st2[c2][1].y);
                __syncthreads();
                if (tid < FCH) {
                    const int h = tid;
                    for (int c2 = 0; c2 < nc; ++c2) {
                        const int k = av[cb + c2] >> 9;
                        const float* wrow = fc1_w + (size_t)h * ((size_t)dlast * IMG) + (size_t)k * IMG;
                        const float* T = s_flat + c2 * TSZ;
                        for (int r = 0; r < HWDIM; ++r) {
                            const float* tr = T + (r + 2) * 32 + 2;
                            const float* wrr = wrow + r * HWDIM;
                            #pragma unroll
                            for (int c = 0; c < HWDIM; c += 4) {
                                float4 w4 = *(const float4*)(wrr + c);
                                acc = fmaf(tr[c],     w4.x, acc);
                                acc = fmaf(tr[c + 1], w4.y, acc);
                                acc = fmaf(tr[c + 2], w4.z, acc);
                                acc = fmaf(tr[c + 3], w4.w, acc);
                            }
                        }
                    }
                }
                __syncthreads();   // LDS reuse guard before next round's writes
            }
            if (tid < FCH) stg1(&hidden[b * FCH + tid], fmaxf(acc, 0.f));
            __syncthreads();
            if (tid == 0)
                __hip_atomic_fetch_add(fcDone, 1, __ATOMIC_RELAXED, __HIP_MEMORY_SCOPE_AGENT);

        } else {
            // -------- FC2 + log_softmax (final unit) --------
            if (tid == 0) wait_count(fcDone, BATCH);
            __syncthreads();
            if (tid < BATCH) {
                const int b = tid;
                float hr[FCH];
                for (int h = 0; h < FCH; h += 2) {
                    float2 v2 = ldg2(&hidden[b * FCH + h]);
                    hr[h] = v2.x; hr[h + 1] = v2.y;
                }
                float lg[NCLS], m = -1e30f;
                #pragma unroll
                for (int c = 0; c < NCLS; ++c) {
                    float a2 = fc2_b[c];
                    const float* wr = fc2_w + c * FCH;
                    for (int h = 0; h < FCH; ++h) a2 = fmaf(hr[h], wr[h], a2);
                    lg[c] = a2;
                    m = fmaxf(m, a2);
                }
                float s = 0.0f;
                #pragma unroll
                for (int c = 0; c < NCLS; ++c) s += expf(lg[c] - m);
                const float ls = m + logf(s);
                #pragma unroll
                for (int c = 0; c < NCLS; ++c) dout[b * NCLS + c] = lg[c] - ls;
            }
        }
    }
}

extern "C" void kernel_launch(void* const* d_in, const int* in_sizes, int n_in,
                              void* d_out, int out_size, void* d_ws, size_t ws_size,
                              hipStream_t stream) {
    const float* x      = (const float*)d_in[0];
    const int*   src    = (const int*)d_in[1];
    const int*   tgt    = (const int*)d_in[2];
    const float* conv_w = (const float*)d_in[3];
    const float* conv_b = (const float*)d_in[4];
    const float* fc1_w  = (const float*)d_in[5];
    const float* fc1_b  = (const float*)d_in[6];
    const float* fc2_w  = (const float*)d_in[7];
    const float* fc2_b  = (const float*)d_in[8];
    float* out = (float*)d_out;
    char*  wsc = (char*)d_ws;

    int cmax  = in_sizes[3] / (N_NEUR * 25);
    int dlast = in_sizes[5] / (FCH * IMG);

    void* kargs[] = { (void*)&x, (void*)&src, (void*)&tgt, (void*)&conv_w, (void*)&conv_b,
                      (void*)&fc1_w, (void*)&fc1_b, (void*)&fc2_w, (void*)&fc2_b,
                      (void*)&out, (void*)&wsc, (void*)&cmax, (void*)&dlast };
    void* kfn = (void*)net_kernel;

    int occ = 0;
    hipError_t qerr = hipOccupancyMaxActiveBlocksPerMultiprocessor(&occ, kfn, NT, 0);
    if (qerr != hipSuccess || occ < 1) occ = 1;
    int nbl = occ * NUM_CU;
    if (nbl > MAX_NB) nbl = MAX_NB;

    for (int attempt = 0; attempt < 6; ++attempt) {
        hipError_t lerr = hipLaunchCooperativeKernel(kfn, dim3(nbl), dim3(NT), kargs, 0, stream);
        if (lerr == hipSuccess) break;
        nbl = (nbl > 64) ? nbl / 2 : 64;
    }
}

// Round 8
// 365.097 us; speedup vs baseline: 2.0003x; 1.0717x over previous
//
#include <hip/hip_runtime.h>
#include <hip/hip_cooperative_groups.h>

namespace cg = cooperative_groups;

#define N_NEUR 256
#define N_EDGE 1024
#define BATCH  128
#define HWDIM  28
#define IMG    784
#define FCH    200
#define NCLS   10
#define INF_W  0x3fffffff

#define MAX_NB 768
#define NT 256
#define NUM_CU 256
#define SLOTS 257        // 256 neurons + 1 slot for staged x
#define XSLOT 256
#define TSZ   1024       // padded 32x32 tile, floats
#define CHUNK 4          // conv channels per LDS round (x BPER batches)
#define FCHUNK 8         // fc1 channels per LDS round
#define BPER  2
#define CONV_TARGET (BATCH / BPER)   // 64 units produce one node

// ---- agent-scope atomic STORES for produced data (proven R7 protocol) ----
__device__ __forceinline__ void stg2(float* p, float a, float b) {
    unsigned long long u = (unsigned long long)__float_as_uint(a)
                         | ((unsigned long long)__float_as_uint(b) << 32);
    __hip_atomic_store((unsigned long long*)p, u, __ATOMIC_RELAXED,
                       __HIP_MEMORY_SCOPE_AGENT);
}
__device__ __forceinline__ void stg1(float* p, float a) {
    __hip_atomic_store((unsigned*)p, __float_as_uint(a), __ATOMIC_RELAXED,
                       __HIP_MEMORY_SCOPE_AGENT);
}

__device__ __forceinline__ void wait_count(int* f, int target) {
    int spins = 0;
    while (__hip_atomic_load(f, __ATOMIC_RELAXED, __HIP_MEMORY_SCOPE_AGENT) < target) {
        if (spins < 16) __builtin_amdgcn_s_sleep(2);
        else            __builtin_amdgcn_s_sleep(16);
        ++spins;
    }
}

// swizzled LDS float-index for (row,col) of a 32x32 tile (bank-spread, 8B-safe)
__device__ __forceinline__ int lcol(int row, int col) {
    return (row << 5) + (col ^ ((row & 7) << 2));
}

__global__ __launch_bounds__(NT, 4)
void net_kernel(const float* __restrict__ x, const int* __restrict__ src,
                const int* __restrict__ tgt,
                const float* __restrict__ conv_w, const float* __restrict__ conv_b,
                const float* __restrict__ fc1_w, const float* __restrict__ fc1_b,
                const float* __restrict__ fc2_w, const float* __restrict__ fc2_b,
                float* __restrict__ dout, char* __restrict__ wsc,
                int cmax, int dlast)
{
    cg::grid_group grid = cg::this_grid();
    const int tid = threadIdx.x;
    const int nb  = gridDim.x;

    float* act    = (float*)wsc;                            // [SLOTS*BATCH][1024]
    float* hidden = act + (size_t)SLOTS * BATCH * TSZ;      // [128][200]
    int* ib        = (int*)(hidden + BATCH * FCH);
    int* inact     = ib;            // [256]
    int* waveOff   = ib + 256;      // [320]
    int* waveNodes = ib + 576;      // [256]
    int* iwaveG    = ib + 832;      // [256]
    int* nodeDone  = ib + 1088;     // [257] per-node completed-unit count
    int* fcDone    = ib + 1348;     // [1]
    int* iidx      = ib + 1352;             // [256*cmax]
    int* iact      = iidx + N_NEUR * cmax;  // [256*cmax] packed u | (c<<9)

    __shared__ float s_tiles[BPER][CHUNK][TSZ];   // 32KB (aliased in phase 0 / FC1)
    __shared__ float s_wgt[CHUNK * 26];
    __shared__ int   s_done;
    float* s_flat = &s_tiles[0][0][0];

    // ================= phase 0: schedule + flag init (block 0) | halo-zero + x (others) ====
    if (blockIdx.x == 0) {
        int* s_src  = (int*)s_flat;
        int* s_tgt  = s_src + N_EDGE;
        int* s_wave = s_tgt + N_EDGE;
        for (int e = tid; e < N_EDGE; e += NT) { s_src[e] = src[e]; s_tgt[e] = tgt[e]; }
        s_wave[tid] = (tid == 0) ? 0 : INF_W;
        nodeDone[tid] = 0;
        if (tid == 0) { nodeDone[XSLOT] = CONV_TARGET; *fcDone = 0; }
        __syncthreads();
        int d = 0;
        for (int e = 0; e < N_EDGE; ++e)
            if (s_tgt[e] == tid) { iidx[tid * cmax + d] = s_src[e]; ++d; }
        __syncthreads();
        for (int w = 0; w < 256; ++w) {
            if (tid == 0) s_done = (s_wave[N_NEUR - 1] != INF_W);
            __syncthreads();
            if (s_done) break;
            for (int e = tid; e < N_EDGE; e += NT) {
                int s = s_src[e], t = s_tgt[e];
                if (s_wave[s] == w && s_wave[t] == INF_W) s_wave[t] = w + 1;
            }
            __syncthreads();
        }
        {   // compact active channels (wave[u] < wave[v]); inactive contribute exact zeros
            const int wv = s_wave[tid];
            int na = 0;
            for (int c = 0; c < d; ++c) {
                int u = iidx[tid * cmax + c];
                if (s_wave[u] < wv) iact[tid * cmax + na++] = u | (c << 9);
            }
            inact[tid] = na;
            if (tid == 0) { iact[0] = XSLOT; inact[0] = 1; }
        }
        __syncthreads();
        {
            const int Wl = s_wave[N_NEUR - 1];
            for (int t2 = tid; t2 <= Wl + 1; t2 += NT) {
                int cn = 0;
                for (int v = 0; v < N_NEUR - 1; ++v) if (s_wave[v] < t2) ++cn;
                waveOff[t2] = cn;
            }
            const int v = tid;
            if (v < N_NEUR - 1 && s_wave[v] != INF_W) {
                const int wv = s_wave[v];
                int pos = 0;
                for (int v2 = 0; v2 < N_NEUR - 1; ++v2) {
                    int w2 = s_wave[v2];
                    if (w2 < wv || (w2 == wv && v2 < v)) ++pos;
                }
                waveNodes[pos] = v;
            }
            iwaveG[tid] = s_wave[tid];
        }
    } else {
        const int base   = (blockIdx.x - 1) * NT + tid;
        const int stride = (nb - 1) * NT;
        const int NTILE  = SLOTS * BATCH;
        for (int u = base; u < NTILE * 72; u += stride) {   // halos
            int t = u % 72;
            float* tp = act + ((size_t)(u / 72) << 10);
            if (t < 16) {
                int eb = (t < 8) ? t * 8 : 960 + (t - 8) * 8;
                float4 z = make_float4(0.f, 0.f, 0.f, 0.f);
                ((float4*)(tp + eb))[0] = z; ((float4*)(tp + eb))[1] = z;
            } else {
                int s = t - 16;
                int eb = (2 + (s >> 1)) * 32 + ((s & 1) ? 30 : 0);
                *((float2*)(tp + eb)) = make_float2(0.f, 0.f);
            }
        }
        for (int u = base; u < BATCH * 196; u += stride) {  // stage x at XSLOT
            int b = u / 196, ch = u - b * 196;
            int row = ch / 7, col = (ch - row * 7) * 4;
            float4 v4 = *(const float4*)(x + b * IMG + row * HWDIM + col);
            float* tp = act + (((size_t)(XSLOT * BATCH + b)) << 10) + (row + 2) * 32 + col + 2;
            tp[0] = v4.x; tp[1] = v4.y; tp[2] = v4.z; tp[3] = v4.w;
        }
    }
    grid.sync();   // ONLY grid-wide barrier: publishes schedule, halos, x, flags

    const int W         = iwaveG[N_NEUR - 1];
    const int nConv     = waveOff[W + 1];
    const int totalConv = nConv * CONV_TARGET;
    const int totalUnits = totalConv + BATCH + 1;

    const int cy = tid / 14, cx = tid - cy * 14;
    const int y0 = cy * 2, x0 = cx * 2;
    const bool cellAct = (tid < 196);
    const int g = tid >> 3, cg4 = (tid & 7) << 2;
    const int di = (g << 5) + (cg4 ^ ((g & 7) << 2));       // swizzled dest for tid's float4

    // ============== dataflow unit loop (topological static assignment) ==============
    // Reads of act/hidden are PLAIN cached vector loads: locations are immutable once
    // their flag is observed, and consumer caches cannot hold stale copies (first-touch
    // happens only after the flag; producers store through agent scope; grid.sync's
    // acq-rel cleaned phase-0 lines). __syncthreads after the spin orders all lanes.
    for (int unit = blockIdx.x; unit < totalUnits; unit += nb) {
        if (unit < totalConv) {
            // -------- conv unit: node waveNodes[ni], batches bp, bp+1 --------
            const int ni = unit >> 6;               // CONV_TARGET == 64
            const int bp = (unit & 63) * BPER;
            const int v  = waveNodes[ni];
            const int na = inact[v];
            const int* av = iact + v * cmax;
            if (tid == 0)
                for (int a = 0; a < na; ++a) wait_count(&nodeDone[av[a] & 511], CONV_TARGET);
            __syncthreads();   // acquire point: all lanes ordered after flag observation

            const float bias = conv_b[v];
            float acc[BPER][4];
            #pragma unroll
            for (int bb = 0; bb < BPER; ++bb)
                #pragma unroll
                for (int k = 0; k < 4; ++k) acc[bb][k] = bias;

            for (int cb = 0; cb < na; cb += CHUNK) {
                const int nc = (na - cb < CHUNK) ? (na - cb) : CHUNK;
                // coalesced float4 staging loads (cacheable, 16B/lane)
                float4 stg[CHUNK][BPER];
                #pragma unroll
                for (int c2 = 0; c2 < CHUNK; ++c2) {
                    if (c2 < nc) {
                        const int u2 = av[cb + c2] & 511;
                        #pragma unroll
                        for (int bb = 0; bb < BPER; ++bb)
                            stg[c2][bb] = *(const float4*)(act +
                                (((size_t)(u2 * BATCH + bp + bb)) << 10) + (tid << 2));
                    }
                }
                float wreg = 0.f;
                if (tid < nc * 25) {
                    const int c2 = tid / 25, k = tid - c2 * 25;
                    const int cc = av[cb + c2] >> 9;
                    wreg = conv_w[((size_t)v * cmax + cc) * 25 + k];
                }
                __syncthreads();   // prior LDS readers done
                #pragma unroll
                for (int c2 = 0; c2 < CHUNK; ++c2) {
                    if (c2 < nc) {
                        #pragma unroll
                        for (int bb = 0; bb < BPER; ++bb)
                            *(float4*)&s_tiles[bb][c2][di] = stg[c2][bb];
                    }
                }
                if (tid < nc * 25) s_wgt[(tid / 25) * 26 + (tid - (tid / 25) * 25)] = wreg;
                __syncthreads();
                if (cellAct) {
                    #pragma unroll
                    for (int bb = 0; bb < BPER; ++bb) {
                        for (int c2 = 0; c2 < nc; ++c2) {
                            float wg[25];
                            #pragma unroll
                            for (int k = 0; k < 25; ++k) wg[k] = s_wgt[c2 * 26 + k];
                            const float* T = &s_tiles[bb][c2][0];
                            #pragma unroll
                            for (int r = 0; r < 6; ++r) {
                                const int row = y0 + r;
                                float2 p0 = *(const float2*)&T[lcol(row, x0)];
                                float2 p1 = *(const float2*)&T[lcol(row, x0 + 2)];
                                float2 p2 = *(const float2*)&T[lcol(row, x0 + 4)];
                                float f[6] = {p0.x, p0.y, p1.x, p1.y, p2.x, p2.y};
                                #pragma unroll
                                for (int i = 0; i < 2; ++i) {
                                    const int wr = r - i;
                                    if (wr < 0 || wr > 4) continue;
                                    #pragma unroll
                                    for (int j = 0; j < 2; ++j)
                                        #pragma unroll
                                        for (int dx = 0; dx < 5; ++dx)
                                            acc[bb][i * 2 + j] =
                                                fmaf(f[j + dx], wg[wr * 5 + dx], acc[bb][i * 2 + j]);
                                }
                            }
                        }
                    }
                }
            }
            if (cellAct) {
                #pragma unroll
                for (int bb = 0; bb < BPER; ++bb) {
                    float* op = act + (((size_t)(v * BATCH + bp + bb)) << 10) + (y0 + 2) * 32 + x0 + 2;
                    stg2(op,      fmaxf(acc[bb][0], 0.f), fmaxf(acc[bb][1], 0.f));
                    stg2(op + 32, fmaxf(acc[bb][2], 0.f), fmaxf(acc[bb][3], 0.f));
                }
            }
            __syncthreads();   // vmcnt(0) drain: all stores globally visible
            if (tid == 0)
                __hip_atomic_fetch_add(&nodeDone[v], 1, __ATOMIC_RELAXED, __HIP_MEMORY_SCOPE_AGENT);

        } else if (unit < totalConv + BATCH) {
            // -------- FC1 unit: one batch b, all 200 hidden --------
            const int b   = unit - totalConv;
            const int naL = inact[N_NEUR - 1];
            const int* av = iact + (N_NEUR - 1) * cmax;
            if (tid == 0)
                for (int a = 0; a < naL; ++a) wait_count(&nodeDone[av[a] & 511], CONV_TARGET);
            __syncthreads();
            float acc = (tid < FCH) ? fc1_b[tid] : 0.f;
            for (int cb = 0; cb < naL; cb += FCHUNK) {
                const int nc = (naL - cb < FCHUNK) ? (naL - cb) : FCHUNK;
                float4 st4[FCHUNK];
                #pragma unroll
                for (int c2 = 0; c2 < FCHUNK; ++c2) {
                    if (c2 < nc) {
                        const int u2 = av[cb + c2] & 511;
                        st4[c2] = *(const float4*)(act +
                            (((size_t)(u2 * BATCH + b)) << 10) + (tid << 2));
                    }
                }
                __syncthreads();
                #pragma unroll
                for (int c2 = 0; c2 < FCHUNK; ++c2)
                    if (c2 < nc)
                        *(float4*)(s_flat + c2 * TSZ + (tid << 2)) = st4[c2];
                __syncthreads();
                if (tid < FCH) {
                    const int h = tid;
                    for (int c2 = 0; c2 < nc; ++c2) {
                        const int k = av[cb + c2] >> 9;
                        const float* wrow = fc1_w + (size_t)h * ((size_t)dlast * IMG) + (size_t)k * IMG;
                        const float* T = s_flat + c2 * TSZ;
                        for (int r = 0; r < HWDIM; ++r) {
                            const float* tr = T + (r + 2) * 32 + 2;
                            const float* wrr = wrow + r * HWDIM;
                            #pragma unroll
                            for (int c = 0; c < HWDIM; c += 4) {
                                float4 w4 = *(const float4*)(wrr + c);
                                acc = fmaf(tr[c],     w4.x, acc);
                                acc = fmaf(tr[c + 1], w4.y, acc);
                                acc = fmaf(tr[c + 2], w4.z, acc);
                                acc = fmaf(tr[c + 3], w4.w, acc);
                            }
                        }
                    }
                }
                __syncthreads();   // LDS reuse guard before next round's writes
            }
            if (tid < FCH) stg1(&hidden[b * FCH + tid], fmaxf(acc, 0.f));
            __syncthreads();
            if (tid == 0)
                __hip_atomic_fetch_add(fcDone, 1, __ATOMIC_RELAXED, __HIP_MEMORY_SCOPE_AGENT);

        } else {
            // -------- FC2 + log_softmax (final unit) --------
            if (tid == 0) wait_count(fcDone, BATCH);
            __syncthreads();
            if (tid < BATCH) {
                const int b = tid;
                float hr[FCH];
                for (int h = 0; h < FCH; h += 2) {
                    float2 v2 = *(const float2*)&hidden[b * FCH + h];
                    hr[h] = v2.x; hr[h + 1] = v2.y;
                }
                float lg[NCLS], m = -1e30f;
                #pragma unroll
                for (int c = 0; c < NCLS; ++c) {
                    float a2 = fc2_b[c];
                    const float* wr = fc2_w + c * FCH;
                    for (int h = 0; h < FCH; ++h) a2 = fmaf(hr[h], wr[h], a2);
                    lg[c] = a2;
                    m = fmaxf(m, a2);
                }
                float s = 0.0f;
                #pragma unroll
                for (int c = 0; c < NCLS; ++c) s += expf(lg[c] - m);
                const float ls = m + logf(s);
                #pragma unroll
                for (int c = 0; c < NCLS; ++c) dout[b * NCLS + c] = lg[c] - ls;
            }
        }
    }
}

extern "C" void kernel_launch(void* const* d_in, const int* in_sizes, int n_in,
                              void* d_out, int out_size, void* d_ws, size_t ws_size,
                              hipStream_t stream) {
    const float* x      = (const float*)d_in[0];
    const int*   src    = (const int*)d_in[1];
    const int*   tgt    = (const int*)d_in[2];
    const float* conv_w = (const float*)d_in[3];
    const float* conv_b = (const float*)d_in[4];
    const float* fc1_w  = (const float*)d_in[5];
    const float* fc1_b  = (const float*)d_in[6];
    const float* fc2_w  = (const float*)d_in[7];
    const float* fc2_b  = (const float*)d_in[8];
    float* out = (float*)d_out;
    char*  wsc = (char*)d_ws;

    int cmax  = in_sizes[3] / (N_NEUR * 25);
    int dlast = in_sizes[5] / (FCH * IMG);

    void* kargs[] = { (void*)&x, (void*)&src, (void*)&tgt, (void*)&conv_w, (void*)&conv_b,
                      (void*)&fc1_w, (void*)&fc1_b, (void*)&fc2_w, (void*)&fc2_b,
                      (void*)&out, (void*)&wsc, (void*)&cmax, (void*)&dlast };
    void* kfn = (void*)net_kernel;

    int occ = 0;
    hipError_t qerr = hipOccupancyMaxActiveBlocksPerMultiprocessor(&occ, kfn, NT, 0);
    if (qerr != hipSuccess || occ < 1) occ = 1;
    int nbl = occ * NUM_CU;
    if (nbl > MAX_NB) nbl = MAX_NB;

    for (int attempt = 0; attempt < 6; ++attempt) {
        hipError_t lerr = hipLaunchCooperativeKernel(kfn, dim3(nbl), dim3(NT), kargs, 0, stream);
        if (lerr == hipSuccess) break;
        nbl = (nbl > 64) ? nbl / 2 : 64;
    }
}

// Round 9
// 320.957 us; speedup vs baseline: 2.2754x; 1.1375x over previous
//
#include <hip/hip_runtime.h>

#define N_NEUR 256
#define N_EDGE 1024
#define BATCH  128
#define HWDIM  28
#define IMG    784
#define FCH    200
#define NCLS   10
#define INF_W  0x3fffffff
#define SLOTS  257        // 256 neurons + X slot
#define XSLOT  256
#define TSZ    1024       // padded 32x32 tile
#define NT1    1024
#define NWAVE  16
#define FCCH   8

// ws layout (floats): act[BATCH][SLOTS][TSZ] | hidden[BATCH][FCH] | gsched(int)[1+N_EDGE]
#define ACT_FLOATS ((size_t)BATCH * SLOTS * TSZ)

// ============================ kernel 1: all convs ============================
// One block per batch element. Block-private slab -> no cross-block traffic.
__global__ __launch_bounds__(NT1, 4)
void conv_kernel(const float* __restrict__ x, const int* __restrict__ src,
                 const int* __restrict__ tgt, const float* __restrict__ conv_w,
                 const float* __restrict__ conv_b, float* __restrict__ act,
                 int* __restrict__ gsched, int cmax)
{
    const int tid = threadIdx.x;
    const int b   = blockIdx.x;

    __shared__ float s_tiles[NWAVE][2][TSZ];   // 128 KB; head aliased in phase 0
    __shared__ int   s_off[N_NEUR + 2];
    __shared__ int   s_dat[N_EDGE];
    __shared__ int   s_wn[N_NEUR];
    __shared__ int   s_wo[N_NEUR + 2];
    __shared__ int   s_na[N_NEUR];
    __shared__ int   s_W;
    __shared__ int   s_done;

    // ---------- phase 0: schedule build (every block, redundant; BFS temp in s_tiles) ------
    int* e_src = (int*)&s_tiles[0][0][0];
    int* e_tgt = e_src + N_EDGE;
    int* wv    = e_tgt + N_EDGE;

    if (tid < N_EDGE) { e_src[tid] = src[tid]; e_tgt[tid] = tgt[tid]; }
    if (tid < N_NEUR) wv[tid] = (tid == 0) ? 0 : INF_W;
    __syncthreads();
    for (int w = 0; w < N_NEUR; ++w) {
        if (tid == 0) s_done = (wv[N_NEUR - 1] != INF_W);
        __syncthreads();
        if (s_done) break;
        {
            int s = e_src[tid], t = e_tgt[tid];   // exactly 1024 threads = 1024 edges
            if (wv[s] == w && wv[t] == INF_W) wv[t] = w + 1;
        }
        __syncthreads();
    }
    if (tid < N_NEUR) {            // active in-channel counts (wave[u] < wave[v])
        int na = 0;
        const int wvv = wv[tid];
        for (int e = 0; e < N_EDGE; ++e)
            if (e_tgt[e] == tid && wv[e_src[e]] < wvv) ++na;
        if (tid == 0) na = 1;      // neuron 0: synthetic X input, channel 0
        s_na[tid] = na;
    }
    __syncthreads();
    if (tid == 0) {
        int o = 0;
        for (int v = 0; v < N_NEUR; ++v) { s_off[v] = o; o += s_na[v]; }
        s_off[N_NEUR] = o;
        s_W = wv[N_NEUR - 1];
    }
    __syncthreads();
    if (tid < N_NEUR) {            // CSR fill: packed u | (c<<9), c = edge-order channel idx
        if (tid == 0) {
            s_dat[s_off[0]] = XSLOT;
        } else {
            int o = s_off[tid], c = 0;
            const int wvv = wv[tid];
            for (int e = 0; e < N_EDGE; ++e) {
                if (e_tgt[e] == tid) {
                    if (wv[e_src[e]] < wvv) s_dat[o++] = e_src[e] | (c << 9);
                    ++c;
                }
            }
        }
    }
    __syncthreads();
    {   // wave-sorted conv node list (excludes FC node 255)
        const int Wl = s_W;
        if (tid <= Wl + 1) {
            int cn = 0;
            for (int v2 = 0; v2 < N_NEUR - 1; ++v2) if (wv[v2] < tid) ++cn;
            s_wo[tid] = cn;
        }
        if (tid < N_NEUR - 1 && wv[tid] <= Wl) {
            int pos = 0; const int mw = wv[tid];
            for (int v2 = 0; v2 < N_NEUR - 1; ++v2) {
                int w2 = wv[v2];
                if (w2 < mw || (w2 == mw && v2 < tid)) ++pos;
            }
            s_wn[pos] = tid;
        }
    }
    __syncthreads();
    {   // publish FC node's list for kernels 2/3 (all blocks write identical values)
        const int naL = s_off[N_NEUR] - s_off[N_NEUR - 1];
        if (tid == 0) gsched[0] = naL;
        if (tid < naL) gsched[1 + tid] = s_dat[s_off[N_NEUR - 1] + tid];
    }
    // zero halos of my 257 tiles (interior always written before read)
    for (int u = tid; u < SLOTS * 72; u += NT1) {
        const int t = u % 72, tile = u / 72;
        float* tp = act + (((size_t)b * SLOTS + tile) << 10);
        if (t < 16) {
            int eb = (t < 8) ? t * 8 : 960 + (t - 8) * 8;
            float4 z = make_float4(0.f, 0.f, 0.f, 0.f);
            ((float4*)(tp + eb))[0] = z; ((float4*)(tp + eb))[1] = z;
        } else {
            int s = t - 16;
            int eb = (2 + (s >> 1)) * 32 + ((s & 1) ? 30 : 0);
            *((float2*)(tp + eb)) = make_float2(0.f, 0.f);
        }
    }
    // stage my batch's x into the X slot
    for (int u = tid; u < 196; u += NT1) {
        const int row = u / 7, col = (u - row * 7) * 4;
        float4 v4 = *(const float4*)(x + b * IMG + row * HWDIM + col);
        float* tp = act + (((size_t)b * SLOTS + XSLOT) << 10) + (row + 2) * 32 + col + 2;
        *(float2*)tp       = make_float2(v4.x, v4.y);
        *(float2*)(tp + 2) = make_float2(v4.z, v4.w);
    }
    __syncthreads();   // s_tiles alias region free from here

    // ---------------- conv main loop: wavefront = one node, 4x4 px per lane ----------------
    const int wid  = tid >> 6;
    const int lane = tid & 63;
    const bool la  = lane < 49;
    const int cy   = lane / 7, cx = lane - 7 * (lane / 7);
    float* buf0 = &s_tiles[wid][0][0];
    float* buf1 = &s_tiles[wid][1][0];

    for (int w = 0; w <= s_W; ++w) {
        for (int ni = s_wo[w] + wid; ni < s_wo[w + 1]; ni += NWAVE) {
            const int v  = __builtin_amdgcn_readfirstlane(s_wn[ni]);
            const int o0 = s_off[v], o1 = s_off[v + 1];
            const float bias = conv_b[v];
            float acc[16];
            #pragma unroll
            for (int k = 0; k < 16; ++k) acc[k] = bias;

            float4 stg[4];
            {   // prefetch first channel's tile
                const int u0 = s_dat[o0] & 511;
                const float4* gs = (const float4*)(act + (((size_t)b * SLOTS + u0) << 10));
                #pragma unroll
                for (int i = 0; i < 4; ++i) stg[i] = gs[lane + 64 * i];
            }
            for (int o = o0; o < o1; ++o) {
                const int pk = __builtin_amdgcn_readfirstlane(s_dat[o]);
                const int c  = pk >> 9;
                float* buf = (o & 1) ? buf1 : buf0;
                // swizzled LDS store of staged tile (float4 idx: row<<3 | group^((row>>2)&7))
                #pragma unroll
                for (int i = 0; i < 4; ++i) {
                    const int fi  = lane + 64 * i;
                    const int row = fi >> 3, cg = fi & 7;
                    ((float4*)buf)[(row << 3) | (cg ^ ((row >> 2) & 7))] = stg[i];
                }
                if (o + 1 < o1) {   // prefetch next channel while computing this one
                    const int un = s_dat[o + 1] & 511;
                    const float4* gs = (const float4*)(act + (((size_t)b * SLOTS + un) << 10));
                    #pragma unroll
                    for (int i = 0; i < 4; ++i) stg[i] = gs[lane + 64 * i];
                }
                const float* wp = conv_w + ((size_t)v * cmax + c) * 25;
                float wg[25];
                #pragma unroll
                for (int k = 0; k < 25; ++k) wg[k] = wp[k];
                if (la) {
                    #pragma unroll
                    for (int r = 0; r < 8; ++r) {
                        const int row = 4 * cy + r;
                        const int sw  = (row >> 2) & 7;
                        float4 fa = ((const float4*)buf)[(row << 3) | (cx ^ sw)];
                        float4 fb = ((const float4*)buf)[(row << 3) | ((cx + 1) ^ sw)];
                        const float f[8] = {fa.x, fa.y, fa.z, fa.w, fb.x, fb.y, fb.z, fb.w};
                        #pragma unroll
                        for (int i = 0; i < 4; ++i) {
                            const int tr = r - i;
                            if (tr < 0 || tr > 4) continue;
                            #pragma unroll
                            for (int dx = 0; dx < 5; ++dx) {
                                const float wvv = wg[tr * 5 + dx];
                                #pragma unroll
                                for (int j = 0; j < 4; ++j)
                                    acc[i * 4 + j] = fmaf(f[j + dx], wvv, acc[i * 4 + j]);
                            }
                        }
                    }
                }
            }
            if (la) {   // relu + store 4x4 cell (rows/cols 2+4cy../2+4cx..)
                float* gd = act + (((size_t)b * SLOTS + v) << 10);
                #pragma unroll
                for (int i = 0; i < 4; ++i) {
                    float* p = gd + (2 + 4 * cy + i) * 32 + 2 + 4 * cx;
                    *(float2*)p       = make_float2(fmaxf(acc[i*4+0], 0.f), fmaxf(acc[i*4+1], 0.f));
                    *(float2*)(p + 2) = make_float2(fmaxf(acc[i*4+2], 0.f), fmaxf(acc[i*4+3], 0.f));
                }
            }
        }
        __syncthreads();   // DAG-wave boundary (intra-block only)
    }
}

// ============================ kernel 2: FC1 ============================
__global__ __launch_bounds__(512, 2)
void fc1_kernel(const float* __restrict__ act, const float* __restrict__ fc1_w,
                const float* __restrict__ fc1_b, float* __restrict__ hidden,
                const int* __restrict__ gsched, int dlast)
{
    const int tid = threadIdx.x;
    const int b   = blockIdx.x;
    __shared__ float s_comp[FCCH][IMG];
    const int naL  = gsched[0];
    const int h    = tid >> 1, half = tid & 1;
    float acc = 0.f;
    for (int cb = 0; cb < naL; cb += FCCH) {
        const int nc = (naL - cb < FCCH) ? (naL - cb) : FCCH;
        __syncthreads();
        for (int idx = tid; idx < nc * IMG; idx += 512) {
            const int a = idx / IMG, px = idx - a * IMG;
            const int u = gsched[1 + cb + a] & 511;
            const int row = px / HWDIM, col = px - row * HWDIM;
            s_comp[a][px] = act[(((size_t)b * SLOTS + u) << 10) + (row + 2) * 32 + col + 2];
        }
        __syncthreads();
        if (h < FCH) {
            for (int a = 0; a < nc; ++a) {
                const int k = gsched[1 + cb + a] >> 9;
                const float4* w4 = (const float4*)(fc1_w + (size_t)h * ((size_t)dlast * IMG)
                                                   + (size_t)k * IMG + half * 392);
                const float4* c4 = (const float4*)(&s_comp[a][half * 392]);
                #pragma unroll 7
                for (int j = 0; j < 98; ++j) {
                    const float4 wv4 = w4[j], cv4 = c4[j];
                    acc = fmaf(cv4.x, wv4.x, acc);
                    acc = fmaf(cv4.y, wv4.y, acc);
                    acc = fmaf(cv4.z, wv4.z, acc);
                    acc = fmaf(cv4.w, wv4.w, acc);
                }
            }
        }
    }
    acc += __shfl_xor(acc, 1);
    if (h < FCH && half == 0) hidden[b * FCH + h] = fmaxf(acc + fc1_b[h], 0.f);
}

// ============================ kernel 3: FC2 + log_softmax ============================
__global__ __launch_bounds__(128, 1)
void fc2_kernel(const float* __restrict__ hidden, const float* __restrict__ fc2_w,
                const float* __restrict__ fc2_b, float* __restrict__ dout)
{
    const int b = threadIdx.x;   // 128 threads, 1 block
    float hr[FCH];
    const float* hp = hidden + b * FCH;
    for (int h = 0; h < FCH; h += 2) {
        float2 v2 = *(const float2*)(hp + h);
        hr[h] = v2.x; hr[h + 1] = v2.y;
    }
    float lg[NCLS], m = -1e30f;
    #pragma unroll
    for (int c = 0; c < NCLS; ++c) {
        float a2 = fc2_b[c];
        const float* wr = fc2_w + c * FCH;
        for (int h = 0; h < FCH; ++h) a2 = fmaf(hr[h], wr[h], a2);
        lg[c] = a2;
        m = fmaxf(m, a2);
    }
    float s = 0.0f;
    #pragma unroll
    for (int c = 0; c < NCLS; ++c) s += expf(lg[c] - m);
    const float ls = m + logf(s);
    #pragma unroll
    for (int c = 0; c < NCLS; ++c) dout[b * NCLS + c] = lg[c] - ls;
}

extern "C" void kernel_launch(void* const* d_in, const int* in_sizes, int n_in,
                              void* d_out, int out_size, void* d_ws, size_t ws_size,
                              hipStream_t stream) {
    const float* x      = (const float*)d_in[0];
    const int*   src    = (const int*)d_in[1];
    const int*   tgt    = (const int*)d_in[2];
    const float* conv_w = (const float*)d_in[3];
    const float* conv_b = (const float*)d_in[4];
    const float* fc1_w  = (const float*)d_in[5];
    const float* fc1_b  = (const float*)d_in[6];
    const float* fc2_w  = (const float*)d_in[7];
    const float* fc2_b  = (const float*)d_in[8];
    float* out = (float*)d_out;
    float* ws  = (float*)d_ws;

    const int cmax  = in_sizes[3] / (N_NEUR * 25);   // conv_w: [256,1,cmax,5,5]
    const int dlast = in_sizes[5] / (FCH * IMG);     // fc1_w:  [200, dlast*784]

    float* act    = ws;
    float* hidden = ws + ACT_FLOATS;
    int*   gsched = (int*)(hidden + BATCH * FCH);

    hipLaunchKernelGGL(conv_kernel, dim3(BATCH), dim3(NT1), 0, stream,
                       x, src, tgt, conv_w, conv_b, act, gsched, cmax);
    hipLaunchKernelGGL(fc1_kernel, dim3(BATCH), dim3(512), 0, stream,
                       act, fc1_w, fc1_b, hidden, gsched, dlast);
    hipLaunchKernelGGL(fc2_kernel, dim3(1), dim3(128), 0, stream,
                       hidden, fc2_w, fc2_b, out);
}